// Round 1
// baseline (302.390 us; speedup 1.0000x reference)
//
#include <hip/hip_runtime.h>

// SepConv: out[b,c,i,j] = sum_{u,v} img[b,c,i+u,j+v] * vert[b,u,i,j] * hori[b,v,i,j]
// B=8, C=3, W=H=512, K=13, Wo=Ho=500.
//
// Mapping: thread = (b, i, j-quad of 4 consecutive j). j0 = 4*tx so every
// global access (img window float4s, vert/hori float4s, out store) is 16B
// aligned. tmp[4][13] register accumulators hold the v-partials so hori is
// applied only once per output (13 FMA) at the end.

#define KK 13
#define NB 8
#define NC 3
#define IW 512
#define IH 512
#define WO 500
#define HO 500

__global__ __launch_bounds__(256) void sepconv_kernel(
    const float* __restrict__ img,
    const float* __restrict__ hori,
    const float* __restrict__ vert,
    float* __restrict__ out)
{
    const int tj = threadIdx.x;                 // j-quad index within row
    const int i  = blockIdx.y * 2 + threadIdx.y;
    const int b  = blockIdx.z;
    if (tj >= HO / 4) return;                   // 125 quads; tx in [0,128)
    const int j0 = tj * 4;

    const size_t khw = (size_t)WO * HO;         // 250000
    const float* vbase = vert + (size_t)b * KK * khw + (size_t)i * HO + j0;
    const float* hbase = hori + (size_t)b * KK * khw + (size_t)i * HO + j0;

    #pragma unroll 1
    for (int c = 0; c < NC; ++c) {
        const float* ibase = img + (((size_t)(b * NC + c) * IW) + i) * IH + j0;

        float tmp[4][KK];
        #pragma unroll
        for (int jq = 0; jq < 4; ++jq)
            #pragma unroll
            for (int v = 0; v < KK; ++v)
                tmp[jq][v] = 0.0f;

        #pragma unroll
        for (int u = 0; u < KK; ++u) {
            const float* rp = ibase + (size_t)u * IH;
            const float4 r0 = *(const float4*)(rp + 0);
            const float4 r1 = *(const float4*)(rp + 4);
            const float4 r2 = *(const float4*)(rp + 8);
            const float4 r3 = *(const float4*)(rp + 12);
            float row[16];
            row[0]  = r0.x; row[1]  = r0.y; row[2]  = r0.z; row[3]  = r0.w;
            row[4]  = r1.x; row[5]  = r1.y; row[6]  = r1.z; row[7]  = r1.w;
            row[8]  = r2.x; row[9]  = r2.y; row[10] = r2.z; row[11] = r2.w;
            row[12] = r3.x; row[13] = r3.y; row[14] = r3.z; row[15] = r3.w;

            const float4 vt = *(const float4*)(vbase + (size_t)u * khw);

            #pragma unroll
            for (int v = 0; v < KK; ++v) {
                tmp[0][v] += row[0 + v] * vt.x;
                tmp[1][v] += row[1 + v] * vt.y;
                tmp[2][v] += row[2 + v] * vt.z;
                tmp[3][v] += row[3 + v] * vt.w;
            }
        }

        float4 o = make_float4(0.f, 0.f, 0.f, 0.f);
        #pragma unroll
        for (int v = 0; v < KK; ++v) {
            const float4 hv = *(const float4*)(hbase + (size_t)v * khw);
            o.x += tmp[0][v] * hv.x;
            o.y += tmp[1][v] * hv.y;
            o.z += tmp[2][v] * hv.z;
            o.w += tmp[3][v] * hv.w;
        }

        float* op = out + (((size_t)(b * NC + c) * WO) + i) * HO + j0;
        *(float4*)op = o;
    }
}

extern "C" void kernel_launch(void* const* d_in, const int* in_sizes, int n_in,
                              void* d_out, int out_size, void* d_ws, size_t ws_size,
                              hipStream_t stream) {
    const float* img  = (const float*)d_in[0];
    const float* hori = (const float*)d_in[1];
    const float* vert = (const float*)d_in[2];
    float* out = (float*)d_out;

    // block: 128 j-quad lanes x 2 output rows; grid: y covers 500 rows / 2, z = batch
    dim3 block(128, 2, 1);
    dim3 grid(1, WO / 2, NB);
    hipLaunchKernelGGL(sepconv_kernel, grid, block, 0, stream, img, hori, vert, out);
}